// Round 1
// baseline (1900.942 us; speedup 1.0000x reference)
//
#include <hip/hip_runtime.h>

#define NNODES 1000000
#define MDIM 128
#define MSGDIM 64
#define NE 16384
#define TWO_E 32768
#define GIN 352   // 2*MEM + MSG + TIME
#define GRROWS 16

typedef unsigned short u16;
typedef unsigned int u32;

typedef __attribute__((ext_vector_type(8))) short bf16x8;
typedef __attribute__((ext_vector_type(4))) float f32x4;
#define MFMA16(a, b, c) __builtin_amdgcn_mfma_f32_16x16x32_bf16((a), (b), (c), 0, 0, 0)

// ---------------- all scratch as device globals: no d_ws dependence ----------------
__device__ u32   g_table[NNODES];            // 4 MB winner table
__device__ float g_hnew[(size_t)TWO_E * MDIM]; // 16 MB GRU outputs (fp32)
__device__ float g_Wr[GIN * MDIM];
__device__ float g_Wz[GIN * MDIM];
__device__ float g_Wi[GIN * MDIM];
__device__ float g_Wh[MDIM * MDIM];
__device__ float g_W1L[MDIM * MDIM];
__device__ float g_W1R[MDIM * MDIM];
__device__ int   g_isbf16;

__device__ __forceinline__ float bf2f(u16 u) {
  return __uint_as_float(((u32)u) << 16);
}
__device__ __forceinline__ u16 f2bf(float f) {
  u32 u = __float_as_uint(f);
  u += 0x7FFFu + ((u >> 16) & 1u);   // round-to-nearest-even
  return (u16)(u >> 16);
}
// dtype-adaptive input load: flag=1 -> bf16 stream, flag=0 -> fp32 stream
__device__ __forceinline__ float ldin(const void* p, size_t i, int f) {
  return f ? bf2f(((const u16*)p)[i]) : ((const float*)p)[i];
}

// ---------------- input dtype detector (runs every call; deterministic) ----------------
__global__ void k_detect(const void* probe) {
  if (blockIdx.x == 0 && threadIdx.x == 0) {
    const u16* p = (const u16*)probe;   // probe = memory table, values ~N(0,1)
    int cnt = 0;
    for (int i = 0; i < 64; ++i) {
      float a = fabsf(bf2f(p[i]));
      if (a == 0.f || (a > 9.765625e-4f && a < 16.f)) ++cnt;
    }
    g_isbf16 = (cnt > 48) ? 1 : 0;
  }
}

// ---------------- winner table init (keeps the template's kernel name) ----------------
__global__ __launch_bounds__(256) void TGN_74861279969393_kernel() {
  int i = blockIdx.x * 256 + threadIdx.x;
  if (i < NNODES) g_table[i] = 0u;
}

// ---------------- weight prep (FP32 FALLBACK PATH ONLY) ----------------
__global__ __launch_bounds__(256) void k_prep(const void* w_ih, const void* w_hh,
                                              const void* lp_w1) {
  if (g_isbf16) return;   // bf16 path reads raw weights directly via MFMA
  int f = 0;
  int i = blockIdx.x * 256 + threadIdx.x;
  const int SZ = GIN * MDIM;  // 45056
  if (i < 3 * SZ) {
    int seg = i / SZ, r = i - seg * SZ;
    int k = r >> 7, d = r & 127;
    int row = seg * 128 + d;
    float v = ldin(w_ih, (size_t)row * GIN + k, f);
    if (seg < 2 && k < 128) v += ldin(w_hh, (size_t)row * 128 + k, f);
    float* dst = (seg == 0) ? g_Wr : ((seg == 1) ? g_Wz : g_Wi);
    dst[r] = v;
  } else {
    int j = i - 3 * SZ;
    if (j < 16384) {
      int k = j >> 7, d = j & 127;
      g_Wh[j] = ldin(w_hh, (size_t)(256 + d) * 128 + k, f);
    } else if (j < 32768) {
      int q = j - 16384; int c = q >> 7, jj = q & 127;
      g_W1L[q] = ldin(lp_w1, (size_t)jj * 256 + c, f);
    } else if (j < 49152) {
      int q = j - 32768; int c = q >> 7, jj = q & 127;
      g_W1R[q] = ldin(lp_w1, (size_t)jj * 256 + 128 + c, f);
    }
  }
}

// ---------------- LastAggregator: atomicMax of (t+1)<<15 | row ----------------
__global__ __launch_bounds__(256) void k_scatter(const int* __restrict__ srcv,
                                                 const int* __restrict__ dstv,
                                                 const int* __restrict__ tv) {
  int g = blockIdx.x * 256 + threadIdx.x;
  if (g >= TWO_E) return;
  int e = (g < NE) ? g : (g - NE);
  int node = (g < NE) ? srcv[e] : dstv[e];
  u32 key = (((u32)(tv[e] + 1)) << 15) | (u32)g;  // t<2^17, g<2^15: exact pack
  atomicMax(&g_table[node], key);
}

// ================= BF16 PATH: MFMA GRU =================
// C[2E, 2*384] = X[2E,352] @ w_ih^T  (accA, 11 k-steps)
//              + X[2E,:128] @ w_hh^T (accB, 4 k-steps)
// Wave w owns col-tiles {g*8 + w, g*8 + w + 4} for gates g=r,z,n -> gate math lane-local.
__global__ __launch_bounds__(256) void k_gru_mfma(
    const void* mem, const int* __restrict__ last_update,
    const int* __restrict__ srcv, const int* __restrict__ dstv,
    const int* __restrict__ tv, const void* raw_msg,
    const void* time_w, const void* time_b,
    const void* w_ih, const void* w_hh,
    const void* b_ih, const void* b_hh) {
  if (!g_isbf16) return;
  __shared__ __align__(16) u16 xs[32][360];   // stride 360: 2-way (free) ds_read_b128
  __shared__ int s_a[32], s_b[32], s_e[32];
  __shared__ float s_dt[32];
  int tid = threadIdx.x;
  int g0 = blockIdx.x * 32;
  if (tid < 32) {
    int g = g0 + tid;
    int e = (g < NE) ? g : (g - NE);
    int a = (g < NE) ? srcv[e] : dstv[e];   // node being updated (h_old = mem[a])
    int b = (g < NE) ? dstv[e] : srcv[e];
    s_a[tid] = a; s_b[tid] = b; s_e[tid] = e;
    s_dt[tid] = (float)(tv[e] - last_update[a]);
  }
  __syncthreads();
  const u16* memu = (const u16*)mem;
  const u16* rmu  = (const u16*)raw_msg;
  const u16* twu  = (const u16*)time_w;
  const u16* tbu  = (const u16*)time_b;
  // stage X[32][352] bf16: 44 16B chunks per row
  for (int ch = tid; ch < 32 * 44; ch += 256) {
    int row = ch / 44, cc = ch - row * 44;
    uint4 v;
    if (cc < 16) {
      v = *(const uint4*)(memu + (size_t)s_a[row] * MDIM + cc * 8);
    } else if (cc < 32) {
      v = *(const uint4*)(memu + (size_t)s_b[row] * MDIM + (cc - 16) * 8);
    } else if (cc < 40) {
      v = *(const uint4*)(rmu + (size_t)s_e[row] * MSGDIM + (cc - 32) * 8);
    } else {
      float dt = s_dt[row];
      u32 pk[4];
      #pragma unroll
      for (int h2 = 0; h2 < 4; ++h2) {
        int k = (cc - 40) * 8 + h2 * 2;
        float cA = cosf(dt * bf2f(twu[k]) + bf2f(tbu[k]));
        float cB = cosf(dt * bf2f(twu[k + 1]) + bf2f(tbu[k + 1]));
        pk[h2] = (u32)f2bf(cA) | ((u32)f2bf(cB) << 16);
      }
      v = make_uint4(pk[0], pk[1], pk[2], pk[3]);
    }
    *(uint4*)&xs[row][cc * 8] = v;
  }
  __syncthreads();

  int w = tid >> 6, l = tid & 63;
  int lr = l & 15, lk = l >> 4;
  const u16* WI = (const u16*)w_ih;   // [384][352] row-major bf16: direct B-frags
  const u16* WH = (const u16*)w_hh;   // [384][128] row-major bf16
  int j0 = w * 16, j1 = (w + 4) * 16; // within-gate col-tile offsets for this wave

  f32x4 accA[2][3][2], accB[2][3][2];
  #pragma unroll
  for (int tr = 0; tr < 2; ++tr)
    #pragma unroll
    for (int g = 0; g < 3; ++g)
      #pragma unroll
      for (int jj = 0; jj < 2; ++jj) {
        accA[tr][g][jj] = (f32x4){0.f, 0.f, 0.f, 0.f};
        accB[tr][g][jj] = (f32x4){0.f, 0.f, 0.f, 0.f};
      }

  for (int kt = 0; kt < 11; ++kt) {
    int k0 = kt * 32;
    bf16x8 a0 = *(const bf16x8*)&xs[lr][k0 + lk * 8];
    bf16x8 a1 = *(const bf16x8*)&xs[16 + lr][k0 + lk * 8];
    #pragma unroll
    for (int gjj = 0; gjj < 6; ++gjj) {
      int g = gjj >> 1, jj = gjj & 1;
      int c = g * 128 + (jj ? j1 : j0) + lr;
      bf16x8 b = *(const bf16x8*)(WI + (size_t)c * GIN + k0 + lk * 8);
      accA[0][g][jj] = MFMA16(a0, b, accA[0][g][jj]);
      accA[1][g][jj] = MFMA16(a1, b, accA[1][g][jj]);
    }
    if (kt < 4) {   // hh GEMM shares A-frags (X[:, :128] == h_old)
      #pragma unroll
      for (int gjj = 0; gjj < 6; ++gjj) {
        int g = gjj >> 1, jj = gjj & 1;
        int c = g * 128 + (jj ? j1 : j0) + lr;
        bf16x8 b = *(const bf16x8*)(WH + (size_t)c * MDIM + k0 + lk * 8);
        accB[0][g][jj] = MFMA16(a0, b, accB[0][g][jj]);
        accB[1][g][jj] = MFMA16(a1, b, accB[1][g][jj]);
      }
    }
  }

  const u16* BI = (const u16*)b_ih;
  const u16* BH = (const u16*)b_hh;
  #pragma unroll
  for (int jj = 0; jj < 2; ++jj) {
    int d = (jj ? j1 : j0) + lr;
    float br = bf2f(BI[d]) + bf2f(BH[d]);
    float bz = bf2f(BI[128 + d]) + bf2f(BH[128 + d]);
    float bi = bf2f(BI[256 + d]);
    float bh = bf2f(BH[256 + d]);
    #pragma unroll
    for (int tr = 0; tr < 2; ++tr) {
      #pragma unroll
      for (int q = 0; q < 4; ++q) {
        int row = tr * 16 + lk * 4 + q;   // C/D: col=lane&15, row=(lane>>4)*4+reg
        float r = 1.f / (1.f + __expf(-(accA[tr][0][jj][q] + accB[tr][0][jj][q] + br)));
        float z = 1.f / (1.f + __expf(-(accA[tr][1][jj][q] + accB[tr][1][jj][q] + bz)));
        float n = tanhf(accA[tr][2][jj][q] + bi + r * (accB[tr][2][jj][q] + bh));
        float h = bf2f(xs[row][d]);       // h_old[d]
        g_hnew[(size_t)(g0 + row) * MDIM + d] = (1.f - z) * n + z * h;
      }
    }
  }
}

// ================= BF16 PATH: MFMA link prediction =================
// P[64][256]: row 2e = [src|pos], row 2e+1 = [src|neg]; preact = P @ lp_w1^T.
__global__ __launch_bounds__(256) void k_lp_mfma(
    const void* mem, const int* __restrict__ srcv,
    const int* __restrict__ posv, const int* __restrict__ negv,
    const void* lp_w1, const void* lp_b1, const void* lp_w2, const void* lp_b2,
    void* outp) {
  if (!g_isbf16) return;
  __shared__ __align__(16) u16 ps[64][264];   // stride 264: 2-way (free) ds_read_b128
  __shared__ int s_hrow[96], s_node[96];
  int tid = threadIdx.x;
  int e0 = blockIdx.x * 32;
  if (tid < 96) {
    int el = tid / 3, role = tid - el * 3;
    int e = e0 + el;
    int node = (role == 0) ? srcv[e] : ((role == 1) ? posv[e] : negv[e]);
    u32 k = g_table[node];
    s_node[tid] = node;
    s_hrow[tid] = k ? (int)(k & 0x7FFFu) : -1;
  }
  __syncthreads();
  const u16* memu = (const u16*)mem;
  for (int ch = tid; ch < 64 * 32; ch += 256) {
    int row = ch >> 5, cc = ch & 31;
    int e = row >> 1;
    int role = (cc < 16) ? 0 : ((row & 1) ? 2 : 1);
    int id = e * 3 + role;
    int col8 = cc & 15;
    int hr = s_hrow[id];
    uint4 v;
    if (hr >= 0) {
      const float* hp = &g_hnew[(size_t)hr * MDIM + col8 * 8];
      float4 f0 = *(const float4*)hp;
      float4 f1 = *(const float4*)(hp + 4);
      v.x = (u32)f2bf(f0.x) | ((u32)f2bf(f0.y) << 16);
      v.y = (u32)f2bf(f0.z) | ((u32)f2bf(f0.w) << 16);
      v.z = (u32)f2bf(f1.x) | ((u32)f2bf(f1.y) << 16);
      v.w = (u32)f2bf(f1.z) | ((u32)f2bf(f1.w) << 16);
    } else {
      v = *(const uint4*)(memu + (size_t)s_node[id] * MDIM + col8 * 8);
    }
    *(uint4*)&ps[row][cc * 8] = v;
  }
  __syncthreads();

  int w = tid >> 6, l = tid & 63;
  int lr = l & 15, lk = l >> 4;
  const u16* W1 = (const u16*)lp_w1;   // [128][256] row-major bf16: direct B-frags
  f32x4 acc[8];
  #pragma unroll
  for (int tc = 0; tc < 8; ++tc) acc[tc] = (f32x4){0.f, 0.f, 0.f, 0.f};
  for (int kt = 0; kt < 8; ++kt) {
    int k0 = kt * 32;
    bf16x8 a = *(const bf16x8*)&ps[w * 16 + lr][k0 + lk * 8];
    #pragma unroll
    for (int tc = 0; tc < 8; ++tc) {
      int c = tc * 16 + lr;
      bf16x8 b = *(const bf16x8*)(W1 + (size_t)c * 256 + k0 + lk * 8);
      acc[tc] = MFMA16(a, b, acc[tc]);
    }
  }
  // s[row] = b2 + sum_j relu(preact[row][j] + b1[j]) * w2[j]
  float part[4] = {0.f, 0.f, 0.f, 0.f};
  #pragma unroll
  for (int tc = 0; tc < 8; ++tc) {
    int j = tc * 16 + lr;
    float b1 = bf2f(((const u16*)lp_b1)[j]);
    float w2 = bf2f(((const u16*)lp_w2)[j]);
    #pragma unroll
    for (int q = 0; q < 4; ++q)
      part[q] = fmaf(fmaxf(acc[tc][q] + b1, 0.f), w2, part[q]);
  }
  #pragma unroll
  for (int off = 1; off < 16; off <<= 1) {
    #pragma unroll
    for (int q = 0; q < 4; ++q) part[q] += __shfl_xor(part[q], off, 64);
  }
  if (lr == 0) {
    float b2 = bf2f(((const u16*)lp_b2)[0]);
    #pragma unroll
    for (int q = 0; q < 4; ++q) {
      int row = w * 16 + lk * 4 + q;
      int e = e0 + (row >> 1);
      u16 s = f2bf(part[q] + b2);
      ((u16*)outp)[(row & 1) ? (NE + e) : e] = s;
    }
  }
}

// ================= FP32 FALLBACK: original VALU kernels =================
__global__ __launch_bounds__(256) void k_gru(
    const void* mem, const int* __restrict__ last_update,
    const int* __restrict__ srcv, const int* __restrict__ dstv,
    const int* __restrict__ tv, const void* raw_msg,
    const void* time_w, const void* time_b,
    const void* b_ih, const void* b_hh) {
  if (g_isbf16) return;   // bf16 handled by k_gru_mfma
  __shared__ float xs[GRROWS][GIN];  // 22.5 KB
  __shared__ int s_node[GRROWS], s_oth[GRROWS], s_e[GRROWS];
  __shared__ float s_dt[GRROWS];
  int f = 0;
  int tid = threadIdx.x;
  int g0 = blockIdx.x * GRROWS;
  if (tid < GRROWS) {
    int g = g0 + tid;
    int e = (g < NE) ? g : (g - NE);
    int a = (g < NE) ? srcv[e] : dstv[e];
    int b = (g < NE) ? dstv[e] : srcv[e];
    s_node[tid] = a; s_oth[tid] = b; s_e[tid] = e;
    s_dt[tid] = (float)(tv[e] - last_update[a]);
  }
  __syncthreads();
  for (int j = tid; j < GRROWS * GIN; j += 256) {
    int row = j / GIN, c = j - row * GIN;
    float v;
    if (c < 128)      v = ldin(mem, (size_t)s_node[row] * MDIM + c, f);
    else if (c < 256) v = ldin(mem, (size_t)s_oth[row] * MDIM + (c - 128), f);
    else if (c < 320) v = ldin(raw_msg, (size_t)s_e[row] * MSGDIM + (c - 256), f);
    else {
      int k = c - 320;
      v = cosf(s_dt[row] * ldin(time_w, k, f) + ldin(time_b, k, f));
    }
    xs[row][c] = v;
  }
  __syncthreads();
  int d = tid & 127, rg = tid >> 7;
  int r0 = rg * 8;
  float ar[8], az[8], ai[8], ah[8];
  #pragma unroll
  for (int i = 0; i < 8; ++i) { ar[i] = 0.f; az[i] = 0.f; ai[i] = 0.f; ah[i] = 0.f; }
  for (int k = 0; k < 128; k += 4) {
    float4 xv[8];
    #pragma unroll
    for (int i = 0; i < 8; ++i) xv[i] = *(const float4*)&xs[r0 + i][k];
    #pragma unroll
    for (int kk = 0; kk < 4; ++kk) {
      int kc = k + kk;
      float wr = g_Wr[kc * 128 + d], wz = g_Wz[kc * 128 + d];
      float wi = g_Wi[kc * 128 + d], wh = g_Wh[kc * 128 + d];
      #pragma unroll
      for (int i = 0; i < 8; ++i) {
        float x = (kk == 0) ? xv[i].x : (kk == 1) ? xv[i].y : (kk == 2) ? xv[i].z : xv[i].w;
        ar[i] = fmaf(wr, x, ar[i]); az[i] = fmaf(wz, x, az[i]);
        ai[i] = fmaf(wi, x, ai[i]); ah[i] = fmaf(wh, x, ah[i]);
      }
    }
  }
  for (int k = 128; k < GIN; k += 4) {
    float4 xv[8];
    #pragma unroll
    for (int i = 0; i < 8; ++i) xv[i] = *(const float4*)&xs[r0 + i][k];
    #pragma unroll
    for (int kk = 0; kk < 4; ++kk) {
      int kc = k + kk;
      float wr = g_Wr[kc * 128 + d], wz = g_Wz[kc * 128 + d], wi = g_Wi[kc * 128 + d];
      #pragma unroll
      for (int i = 0; i < 8; ++i) {
        float x = (kk == 0) ? xv[i].x : (kk == 1) ? xv[i].y : (kk == 2) ? xv[i].z : xv[i].w;
        ar[i] = fmaf(wr, x, ar[i]); az[i] = fmaf(wz, x, az[i]); ai[i] = fmaf(wi, x, ai[i]);
      }
    }
  }
  float br = ldin(b_ih, d, f) + ldin(b_hh, d, f);
  float bz = ldin(b_ih, 128 + d, f) + ldin(b_hh, 128 + d, f);
  float bi = ldin(b_ih, 256 + d, f);
  float bh = ldin(b_hh, 256 + d, f);
  #pragma unroll
  for (int i = 0; i < 8; ++i) {
    float rr = 1.f / (1.f + __expf(-(ar[i] + br)));
    float zz = 1.f / (1.f + __expf(-(az[i] + bz)));
    float nn = tanhf(ai[i] + bi + rr * (ah[i] + bh));
    float h = xs[r0 + i][d];
    g_hnew[(size_t)(g0 + r0 + i) * MDIM + d] = (1.f - zz) * nn + zz * h;
  }
}

__global__ __launch_bounds__(256) void k_linkpred(
    const void* mem, const int* __restrict__ srcv,
    const int* __restrict__ posv, const int* __restrict__ negv,
    const void* lp_b1, const void* lp_w2, const void* lp_b2,
    void* outp) {
  if (g_isbf16) return;   // bf16 handled by k_lp_mfma
  __shared__ float semb[48][MDIM];
  __shared__ int s_hrow[48], s_nd[48];
  int f = 0;
  int tid = threadIdx.x;
  int e0 = blockIdx.x * 16;
  if (tid < 48) {
    int el = tid / 3, role = tid - el * 3;
    int e = e0 + el;
    int node = (role == 0) ? srcv[e] : ((role == 1) ? posv[e] : negv[e]);
    u32 k = g_table[node];
    s_nd[tid] = node;
    s_hrow[tid] = k ? (int)(k & 0x7FFFu) : -1;
  }
  __syncthreads();
  for (int j = tid; j < 48 * MDIM; j += 256) {
    int er = j >> 7, c = j & 127;
    int hr = s_hrow[er];
    semb[er][c] = (hr >= 0) ? g_hnew[(size_t)hr * MDIM + c]
                            : ldin(mem, (size_t)s_nd[er] * MDIM + c, f);
  }
  __syncthreads();
  int wave = tid >> 6, lane = tid & 63;
  float ua0[4], ua1[4], vp0[4], vp1[4], vn0[4], vn1[4];
  #pragma unroll
  for (int i = 0; i < 4; ++i) { ua0[i]=0.f; ua1[i]=0.f; vp0[i]=0.f; vp1[i]=0.f; vn0[i]=0.f; vn1[i]=0.f; }
  for (int c = 0; c < 128; ++c) {
    float l0 = g_W1L[c * 128 + lane], l1 = g_W1L[c * 128 + 64 + lane];
    float q0 = g_W1R[c * 128 + lane], q1 = g_W1R[c * 128 + 64 + lane];
    #pragma unroll
    for (int i = 0; i < 4; ++i) {
      int base = (wave * 4 + i) * 3;
      float a = semb[base][c], p = semb[base + 1][c], n = semb[base + 2][c];
      ua0[i] = fmaf(l0, a, ua0[i]); ua1[i] = fmaf(l1, a, ua1[i]);
      vp0[i] = fmaf(q0, p, vp0[i]); vp1[i] = fmaf(q1, p, vp1[i]);
      vn0[i] = fmaf(q0, n, vn0[i]); vn1[i] = fmaf(q1, n, vn1[i]);
    }
  }
  float b1a = ldin(lp_b1, lane, f), b1b = ldin(lp_b1, 64 + lane, f);
  float w2a = ldin(lp_w2, lane, f), w2b = ldin(lp_w2, 64 + lane, f);
  float b2 = ldin(lp_b2, 0, f);
  #pragma unroll
  for (int i = 0; i < 4; ++i) {
    int e = e0 + wave * 4 + i;
    float hp0 = fmaxf(ua0[i] + vp0[i] + b1a, 0.f);
    float hp1 = fmaxf(ua1[i] + vp1[i] + b1b, 0.f);
    float hq0 = fmaxf(ua0[i] + vn0[i] + b1a, 0.f);
    float hq1 = fmaxf(ua1[i] + vn1[i] + b1b, 0.f);
    float sp = w2a * hp0 + w2b * hp1;
    float sn = w2a * hq0 + w2b * hq1;
    #pragma unroll
    for (int off = 32; off > 0; off >>= 1) {
      sp += __shfl_down(sp, off, 64);
      sn += __shfl_down(sn, off, 64);
    }
    if (lane == 0) {
      ((float*)outp)[e] = sp + b2;
      ((float*)outp)[NE + e] = sn + b2;
    }
  }
}

extern "C" __attribute__((visibility("default")))
void kernel_launch(void* const* d_in, const int* in_sizes, int n_in,
                   void* d_out, int out_size, void* d_ws, size_t ws_size,
                   hipStream_t stream) {
  (void)in_sizes; (void)n_in; (void)out_size; (void)d_ws; (void)ws_size;
  const void* mem        = d_in[0];
  const int* last_update = (const int*)d_in[1];
  const int* srcv        = (const int*)d_in[2];
  const int* posv        = (const int*)d_in[3];
  const int* negv        = (const int*)d_in[4];
  const int* tv          = (const int*)d_in[5];
  const void* raw_msg    = d_in[6];
  const void* time_w     = d_in[7];
  const void* time_b     = d_in[8];
  const void* gw_ih      = d_in[9];
  const void* gw_hh      = d_in[10];
  const void* gb_ih      = d_in[11];
  const void* gb_hh      = d_in[12];
  const void* lp_w1      = d_in[13];
  const void* lp_b1      = d_in[14];
  const void* lp_w2      = d_in[15];
  const void* lp_b2      = d_in[16];

  hipStream_t s = stream;
  k_detect<<<1, 64, 0, s>>>(mem);
  if (hipGetLastError() != hipSuccess) {     // passed stream unusable -> fall back
    s = 0;
    k_detect<<<1, 64, 0, s>>>(mem);
  }
  // diagnostic sentinel: bf16 3.0 pattern; overwritten by linkpred when alive
  hipMemsetAsync(d_out, 0x40, (size_t)TWO_E * sizeof(u16), s);
  TGN_74861279969393_kernel<<<(NNODES + 255) / 256, 256, 0, s>>>();
  k_prep<<<720, 256, 0, s>>>(gw_ih, gw_hh, lp_w1);
  k_scatter<<<TWO_E / 256, 256, 0, s>>>(srcv, posv, tv);
  // bf16 path (early-exits in fp32 mode)
  k_gru_mfma<<<TWO_E / 32, 256, 0, s>>>(mem, last_update, srcv, posv, tv, raw_msg,
                                        time_w, time_b, gw_ih, gw_hh, gb_ih, gb_hh);
  // fp32 fallback (early-exits in bf16 mode)
  k_gru<<<TWO_E / GRROWS, 256, 0, s>>>(mem, last_update, srcv, posv, tv, raw_msg,
                                       time_w, time_b, gb_ih, gb_hh);
  k_lp_mfma<<<NE / 32, 256, 0, s>>>(mem, srcv, posv, negv,
                                    lp_w1, lp_b1, lp_w2, lp_b2, d_out);
  k_linkpred<<<NE / 16, 256, 0, s>>>(mem, srcv, posv, negv,
                                     lp_b1, lp_w2, lp_b2, d_out);
}

// Round 2
// 757.300 us; speedup vs baseline: 2.5102x; 2.5102x over previous
//
#include <hip/hip_runtime.h>

#define NNODES 1000000
#define MDIM 128
#define MSGDIM 64
#define NE 16384
#define TWO_E 32768
#define GIN 352   // 2*MEM + MSG + TIME

typedef unsigned short u16;
typedef unsigned int u32;

typedef __attribute__((ext_vector_type(8))) short bf16x8;
typedef __attribute__((ext_vector_type(4))) float f32x4;
#define MFMA16(a, b, c) __builtin_amdgcn_mfma_f32_16x16x32_bf16((a), (b), (c), 0, 0, 0)

// ---------------- all scratch as device globals: no d_ws dependence ----------------
__device__ u32   g_table[NNODES];              // 4 MB winner table
__device__ float g_hnew[(size_t)TWO_E * MDIM]; // 16 MB GRU outputs (fp32)
// bf16x3 split weights (fp32 input path only): hi/lo pairs, same row-major layout
__device__ u16 g_wih_h[384 * GIN],  g_wih_l[384 * GIN];    // [384][352]
__device__ u16 g_whh_h[384 * MDIM], g_whh_l[384 * MDIM];   // [384][128]
__device__ u16 g_w1_h[128 * 256],   g_w1_l[128 * 256];     // [128][256]
__device__ int g_isbf16;

__device__ __forceinline__ float bf2f(u16 u) {
  return __uint_as_float(((u32)u) << 16);
}
__device__ __forceinline__ u16 f2bf(float f) {
  u32 u = __float_as_uint(f);
  u += 0x7FFFu + ((u >> 16) & 1u);   // round-to-nearest-even
  return (u16)(u >> 16);
}
// dtype-adaptive scalar load: flag=1 -> bf16 stream, flag=0 -> fp32 stream
__device__ __forceinline__ float ldin(const void* p, size_t i, int f) {
  return f ? bf2f(((const u16*)p)[i]) : ((const float*)p)[i];
}
// split 8 fp32 -> packed bf16 hi/lo words (bf16x3 decomposition)
__device__ __forceinline__ void split8(const float* vv, u32* hw, u32* lw) {
  #pragma unroll
  for (int e = 0; e < 4; ++e) {
    u16 h0 = f2bf(vv[2 * e]), h1 = f2bf(vv[2 * e + 1]);
    u16 l0 = f2bf(vv[2 * e] - bf2f(h0));
    u16 l1 = f2bf(vv[2 * e + 1] - bf2f(h1));
    hw[e] = (u32)h0 | ((u32)h1 << 16);
    lw[e] = (u32)l0 | ((u32)l1 << 16);
  }
}

// ---------------- input dtype detector (runs every call; deterministic) ----------------
__global__ void k_detect(const void* probe) {
  if (blockIdx.x == 0 && threadIdx.x == 0) {
    const u16* p = (const u16*)probe;   // probe = memory table, values ~N(0,1)
    int cnt = 0;
    for (int i = 0; i < 64; ++i) {
      float a = fabsf(bf2f(p[i]));
      if (a == 0.f || (a > 9.765625e-4f && a < 16.f)) ++cnt;
    }
    g_isbf16 = (cnt > 48) ? 1 : 0;
  }
}

// ---------------- winner table init (keeps the template's kernel name) ----------------
__global__ __launch_bounds__(256) void TGN_74861279969393_kernel() {
  int i = blockIdx.x * 256 + threadIdx.x;
  if (i < NNODES) g_table[i] = 0u;
}

// ---------------- weight split prep (fp32 input path only; 217088 elems) ----------------
__global__ __launch_bounds__(256) void k_prep2(const void* w_ih, const void* w_hh,
                                               const void* lp_w1) {
  if (g_isbf16) return;   // bf16 inputs: kernels read raw weights directly
  int i = blockIdx.x * 256 + threadIdx.x;
  const int N1 = 384 * GIN, N2 = 384 * MDIM;
  float v; u16 *dh, *dl; int idx;
  if (i < N1)           { idx = i;            v = ((const float*)w_ih)[idx];  dh = g_wih_h; dl = g_wih_l; }
  else if (i < N1 + N2) { idx = i - N1;       v = ((const float*)w_hh)[idx];  dh = g_whh_h; dl = g_whh_l; }
  else                  { idx = i - N1 - N2;  v = ((const float*)lp_w1)[idx]; dh = g_w1_h;  dl = g_w1_l; }
  u16 h = f2bf(v);
  dh[idx] = h;
  dl[idx] = f2bf(v - bf2f(h));
}

// ---------------- LastAggregator: atomicMax of (t+1)<<15 | row ----------------
__global__ __launch_bounds__(256) void k_scatter(const int* __restrict__ srcv,
                                                 const int* __restrict__ dstv,
                                                 const int* __restrict__ tv) {
  int g = blockIdx.x * 256 + threadIdx.x;
  if (g >= TWO_E) return;
  int e = (g < NE) ? g : (g - NE);
  int node = (g < NE) ? srcv[e] : dstv[e];
  u32 key = (((u32)(tv[e] + 1)) << 15) | (u32)g;  // t<2^17, g<2^15: exact pack
  atomicMax(&g_table[node], key);
}

// ================= MFMA GRU (both dtypes; fp32 via bf16x3 split) =================
// C[2E, 384] = X[2E,352] @ w_ih^T  (accA, 11 k-steps)
//            + X[2E,:128] @ w_hh^T (accB, 4 k-steps)
// Wave w owns col-tiles {g*8+w, g*8+w+4} per gate g -> all gates of dim d lane-local.
__global__ __launch_bounds__(256) void k_gru_mfma(
    const void* mem, const int* __restrict__ last_update,
    const int* __restrict__ srcv, const int* __restrict__ dstv,
    const int* __restrict__ tv, const void* raw_msg,
    const void* time_w, const void* time_b,
    const void* w_ih, const void* w_hh,
    const void* b_ih, const void* b_hh) {
  __shared__ __align__(16) u16 xs_h[32][360];   // stride 360: 2-way (free) ds_read_b128
  __shared__ __align__(16) u16 xs_l[32][360];   // lo halves (fp32 path only)
  __shared__ int s_a[32], s_b[32], s_e[32];
  __shared__ float s_dt[32];
  int f = g_isbf16;
  int tid = threadIdx.x;
  int g0 = blockIdx.x * 32;
  if (tid < 32) {
    int g = g0 + tid;
    int e = (g < NE) ? g : (g - NE);
    int a = (g < NE) ? srcv[e] : dstv[e];   // node being updated (h_old = mem[a])
    int b = (g < NE) ? dstv[e] : srcv[e];
    s_a[tid] = a; s_b[tid] = b; s_e[tid] = e;
    s_dt[tid] = (float)(tv[e] - last_update[a]);
  }
  __syncthreads();
  // stage X[32][352]: 44 8-elem chunks per row
  for (int ch = tid; ch < 32 * 44; ch += 256) {
    int row = ch / 44, cc = ch - row * 44;
    if (f) {
      const u16* memu = (const u16*)mem;
      uint4 v;
      if (cc < 16) {
        v = *(const uint4*)(memu + (size_t)s_a[row] * MDIM + cc * 8);
      } else if (cc < 32) {
        v = *(const uint4*)(memu + (size_t)s_b[row] * MDIM + (cc - 16) * 8);
      } else if (cc < 40) {
        v = *(const uint4*)((const u16*)raw_msg + (size_t)s_e[row] * MSGDIM + (cc - 32) * 8);
      } else {
        float dt = s_dt[row];
        u32 pk[4];
        #pragma unroll
        for (int h2 = 0; h2 < 4; ++h2) {
          int k = (cc - 40) * 8 + h2 * 2;
          float cA = cosf(dt * ldin(time_w, k, 1) + ldin(time_b, k, 1));
          float cB = cosf(dt * ldin(time_w, k + 1, 1) + ldin(time_b, k + 1, 1));
          pk[h2] = (u32)f2bf(cA) | ((u32)f2bf(cB) << 16);
        }
        v = make_uint4(pk[0], pk[1], pk[2], pk[3]);
      }
      *(uint4*)&xs_h[row][cc * 8] = v;
    } else {
      const float* memf = (const float*)mem;
      float vv[8];
      if (cc < 40) {
        const float* p;
        if (cc < 16)      p = memf + (size_t)s_a[row] * MDIM + cc * 8;
        else if (cc < 32) p = memf + (size_t)s_b[row] * MDIM + (cc - 16) * 8;
        else              p = (const float*)raw_msg + (size_t)s_e[row] * MSGDIM + (cc - 32) * 8;
        float4 q0 = *(const float4*)p, q1 = *(const float4*)(p + 4);
        vv[0] = q0.x; vv[1] = q0.y; vv[2] = q0.z; vv[3] = q0.w;
        vv[4] = q1.x; vv[5] = q1.y; vv[6] = q1.z; vv[7] = q1.w;
      } else {
        float dt = s_dt[row];
        #pragma unroll
        for (int e = 0; e < 8; ++e) {
          int k = (cc - 40) * 8 + e;
          vv[e] = cosf(dt * ((const float*)time_w)[k] + ((const float*)time_b)[k]);
        }
      }
      u32 hw[4], lw[4];
      split8(vv, hw, lw);
      *(uint4*)&xs_h[row][cc * 8] = make_uint4(hw[0], hw[1], hw[2], hw[3]);
      *(uint4*)&xs_l[row][cc * 8] = make_uint4(lw[0], lw[1], lw[2], lw[3]);
    }
  }
  __syncthreads();

  int w = tid >> 6, l = tid & 63;
  int lr = l & 15, lk = l >> 4;
  const u16* WIh = f ? (const u16*)w_ih : g_wih_h;   // [384][352] bf16 hi
  const u16* WHh = f ? (const u16*)w_hh : g_whh_h;   // [384][128] bf16 hi
  int j0 = w * 16, j1 = (w + 4) * 16;   // within-gate col-tile offsets for this wave

  f32x4 accA[2][3][2], accB[2][3][2];
  #pragma unroll
  for (int tr = 0; tr < 2; ++tr)
    #pragma unroll
    for (int g = 0; g < 3; ++g)
      #pragma unroll
      for (int jj = 0; jj < 2; ++jj) {
        accA[tr][g][jj] = (f32x4){0.f, 0.f, 0.f, 0.f};
        accB[tr][g][jj] = (f32x4){0.f, 0.f, 0.f, 0.f};
      }

  for (int kt = 0; kt < 11; ++kt) {
    int ko = kt * 32 + lk * 8;
    bf16x8 a0h = *(const bf16x8*)&xs_h[lr][ko];
    bf16x8 a1h = *(const bf16x8*)&xs_h[16 + lr][ko];
    bf16x8 a0l, a1l;
    if (!f) {
      a0l = *(const bf16x8*)&xs_l[lr][ko];
      a1l = *(const bf16x8*)&xs_l[16 + lr][ko];
    }
    #pragma unroll
    for (int gjj = 0; gjj < 6; ++gjj) {
      int g = gjj >> 1, jj = gjj & 1;
      int c = g * 128 + (jj ? j1 : j0) + lr;
      size_t off = (size_t)c * GIN + ko;
      bf16x8 bh = *(const bf16x8*)(WIh + off);
      accA[0][g][jj] = MFMA16(a0h, bh, accA[0][g][jj]);
      accA[1][g][jj] = MFMA16(a1h, bh, accA[1][g][jj]);
      if (!f) {   // bf16x3: + a_lo*b_hi + a_hi*b_lo
        bf16x8 bl = *(const bf16x8*)(g_wih_l + off);
        accA[0][g][jj] = MFMA16(a0l, bh, accA[0][g][jj]);
        accA[0][g][jj] = MFMA16(a0h, bl, accA[0][g][jj]);
        accA[1][g][jj] = MFMA16(a1l, bh, accA[1][g][jj]);
        accA[1][g][jj] = MFMA16(a1h, bl, accA[1][g][jj]);
      }
    }
    if (kt < 4) {   // hh GEMM shares A-frags (X[:, :128] == h_old)
      #pragma unroll
      for (int gjj = 0; gjj < 6; ++gjj) {
        int g = gjj >> 1, jj = gjj & 1;
        int c = g * 128 + (jj ? j1 : j0) + lr;
        size_t off = (size_t)c * MDIM + ko;
        bf16x8 bh = *(const bf16x8*)(WHh + off);
        accB[0][g][jj] = MFMA16(a0h, bh, accB[0][g][jj]);
        accB[1][g][jj] = MFMA16(a1h, bh, accB[1][g][jj]);
        if (!f) {
          bf16x8 bl = *(const bf16x8*)(g_whh_l + off);
          accB[0][g][jj] = MFMA16(a0l, bh, accB[0][g][jj]);
          accB[0][g][jj] = MFMA16(a0h, bl, accB[0][g][jj]);
          accB[1][g][jj] = MFMA16(a1l, bh, accB[1][g][jj]);
          accB[1][g][jj] = MFMA16(a1h, bl, accB[1][g][jj]);
        }
      }
    }
  }

  #pragma unroll
  for (int jj = 0; jj < 2; ++jj) {
    int d = (jj ? j1 : j0) + lr;
    float br = ldin(b_ih, d, f) + ldin(b_hh, d, f);
    float bz = ldin(b_ih, 128 + d, f) + ldin(b_hh, 128 + d, f);
    float bi = ldin(b_ih, 256 + d, f);
    float bh = ldin(b_hh, 256 + d, f);
    #pragma unroll
    for (int tr = 0; tr < 2; ++tr) {
      #pragma unroll
      for (int q = 0; q < 4; ++q) {
        int row = tr * 16 + lk * 4 + q;   // C/D: col=lane&15, row=(lane>>4)*4+reg
        float r = 1.f / (1.f + __expf(-(accA[tr][0][jj][q] + accB[tr][0][jj][q] + br)));
        float z = 1.f / (1.f + __expf(-(accA[tr][1][jj][q] + accB[tr][1][jj][q] + bz)));
        float n = tanhf(accA[tr][2][jj][q] + bi + r * (accB[tr][2][jj][q] + bh));
        float h = bf2f(xs_h[row][d]);
        if (!f) h += bf2f(xs_l[row][d]);   // reconstruct fp32 h_old (err ~2^-18)
        g_hnew[(size_t)(g0 + row) * MDIM + d] = (1.f - z) * n + z * h;
      }
    }
  }
}

// ================= MFMA link prediction (both dtypes; fp32 via bf16x3) =================
// P[64][256]: row 2e = [src|pos], row 2e+1 = [src|neg]; preact = P @ lp_w1^T.
__global__ __launch_bounds__(256) void k_lp_mfma(
    const void* mem, const int* __restrict__ srcv,
    const int* __restrict__ posv, const int* __restrict__ negv,
    const void* lp_w1, const void* lp_b1, const void* lp_w2, const void* lp_b2,
    void* outp) {
  __shared__ __align__(16) u16 ps_h[64][264];   // stride 264: 2-way (free) ds_read_b128
  __shared__ __align__(16) u16 ps_l[64][264];
  __shared__ int s_hrow[96], s_node[96];
  int f = g_isbf16;
  int tid = threadIdx.x;
  int e0 = blockIdx.x * 32;
  if (tid < 96) {
    int el = tid / 3, role = tid - el * 3;
    int e = e0 + el;
    int node = (role == 0) ? srcv[e] : ((role == 1) ? posv[e] : negv[e]);
    u32 k = g_table[node];
    s_node[tid] = node;
    s_hrow[tid] = k ? (int)(k & 0x7FFFu) : -1;
  }
  __syncthreads();
  for (int ch = tid; ch < 64 * 32; ch += 256) {
    int row = ch >> 5, cc = ch & 31;
    int e = row >> 1;
    int role = (cc < 16) ? 0 : ((row & 1) ? 2 : 1);
    int id = e * 3 + role;
    int col8 = cc & 15;
    int hr = s_hrow[id];
    if (f) {
      uint4 v;
      if (hr >= 0) {
        const float* hp = &g_hnew[(size_t)hr * MDIM + col8 * 8];
        float4 f0 = *(const float4*)hp;
        float4 f1 = *(const float4*)(hp + 4);
        v.x = (u32)f2bf(f0.x) | ((u32)f2bf(f0.y) << 16);
        v.y = (u32)f2bf(f0.z) | ((u32)f2bf(f0.w) << 16);
        v.z = (u32)f2bf(f1.x) | ((u32)f2bf(f1.y) << 16);
        v.w = (u32)f2bf(f1.z) | ((u32)f2bf(f1.w) << 16);
      } else {
        v = *(const uint4*)((const u16*)mem + (size_t)s_node[id] * MDIM + col8 * 8);
      }
      *(uint4*)&ps_h[row][cc * 8] = v;
    } else {
      const float* p = (hr >= 0) ? &g_hnew[(size_t)hr * MDIM + col8 * 8]
                                 : (const float*)mem + (size_t)s_node[id] * MDIM + col8 * 8;
      float4 q0 = *(const float4*)p, q1 = *(const float4*)(p + 4);
      float vv[8] = {q0.x, q0.y, q0.z, q0.w, q1.x, q1.y, q1.z, q1.w};
      u32 hw[4], lw[4];
      split8(vv, hw, lw);
      *(uint4*)&ps_h[row][cc * 8] = make_uint4(hw[0], hw[1], hw[2], hw[3]);
      *(uint4*)&ps_l[row][cc * 8] = make_uint4(lw[0], lw[1], lw[2], lw[3]);
    }
  }
  __syncthreads();

  int w = tid >> 6, l = tid & 63;
  int lr = l & 15, lk = l >> 4;
  const u16* W1h = f ? (const u16*)lp_w1 : g_w1_h;   // [128][256] bf16 hi
  f32x4 acc[8];
  #pragma unroll
  for (int tc = 0; tc < 8; ++tc) acc[tc] = (f32x4){0.f, 0.f, 0.f, 0.f};
  for (int kt = 0; kt < 8; ++kt) {
    int ko = kt * 32 + lk * 8;
    bf16x8 ah = *(const bf16x8*)&ps_h[w * 16 + lr][ko];
    bf16x8 al;
    if (!f) al = *(const bf16x8*)&ps_l[w * 16 + lr][ko];
    #pragma unroll
    for (int tc = 0; tc < 8; ++tc) {
      int c = tc * 16 + lr;
      size_t off = (size_t)c * 256 + ko;
      bf16x8 bh = *(const bf16x8*)(W1h + off);
      acc[tc] = MFMA16(ah, bh, acc[tc]);
      if (!f) {
        bf16x8 bl = *(const bf16x8*)(g_w1_l + off);
        acc[tc] = MFMA16(al, bh, acc[tc]);
        acc[tc] = MFMA16(ah, bl, acc[tc]);
      }
    }
  }
  // s[row] = b2 + sum_j relu(preact[row][j] + b1[j]) * w2[j]
  float part[4] = {0.f, 0.f, 0.f, 0.f};
  #pragma unroll
  for (int tc = 0; tc < 8; ++tc) {
    int j = tc * 16 + lr;
    float b1 = ldin(lp_b1, j, f);
    float w2 = ldin(lp_w2, j, f);
    #pragma unroll
    for (int q = 0; q < 4; ++q)
      part[q] = fmaf(fmaxf(acc[tc][q] + b1, 0.f), w2, part[q]);
  }
  #pragma unroll
  for (int off = 1; off < 16; off <<= 1) {
    #pragma unroll
    for (int q = 0; q < 4; ++q) part[q] += __shfl_xor(part[q], off, 64);
  }
  if (lr == 0) {
    float b2 = ldin(lp_b2, 0, f);
    #pragma unroll
    for (int q = 0; q < 4; ++q) {
      int row = w * 16 + lk * 4 + q;
      int e = e0 + (row >> 1);
      float s = part[q] + b2;
      size_t oi = (row & 1) ? ((size_t)NE + e) : (size_t)e;
      if (f) ((u16*)outp)[oi] = f2bf(s);
      else   ((float*)outp)[oi] = s;
    }
  }
}

extern "C" __attribute__((visibility("default")))
void kernel_launch(void* const* d_in, const int* in_sizes, int n_in,
                   void* d_out, int out_size, void* d_ws, size_t ws_size,
                   hipStream_t stream) {
  (void)in_sizes; (void)n_in; (void)out_size; (void)d_ws; (void)ws_size;
  const void* mem        = d_in[0];
  const int* last_update = (const int*)d_in[1];
  const int* srcv        = (const int*)d_in[2];
  const int* posv        = (const int*)d_in[3];
  const int* negv        = (const int*)d_in[4];
  const int* tv          = (const int*)d_in[5];
  const void* raw_msg    = d_in[6];
  const void* time_w     = d_in[7];
  const void* time_b     = d_in[8];
  const void* gw_ih      = d_in[9];
  const void* gw_hh      = d_in[10];
  const void* gb_ih      = d_in[11];
  const void* gb_hh      = d_in[12];
  const void* lp_w1      = d_in[13];
  const void* lp_b1      = d_in[14];
  const void* lp_w2      = d_in[15];
  const void* lp_b2      = d_in[16];

  hipStream_t s = stream;
  k_detect<<<1, 64, 0, s>>>(mem);
  if (hipGetLastError() != hipSuccess) {     // passed stream unusable -> fall back
    s = 0;
    k_detect<<<1, 64, 0, s>>>(mem);
  }
  // diagnostic sentinel (overwritten by k_lp_mfma when alive)
  hipMemsetAsync(d_out, 0x40, (size_t)TWO_E * sizeof(u16), s);
  TGN_74861279969393_kernel<<<(NNODES + 255) / 256, 256, 0, s>>>();
  k_prep2<<<(384 * GIN + 384 * MDIM + 128 * 256) / 256, 256, 0, s>>>(gw_ih, gw_hh, lp_w1);
  k_scatter<<<TWO_E / 256, 256, 0, s>>>(srcv, posv, tv);
  k_gru_mfma<<<TWO_E / 32, 256, 0, s>>>(mem, last_update, srcv, posv, tv, raw_msg,
                                        time_w, time_b, gw_ih, gw_hh, gb_ih, gb_hh);
  k_lp_mfma<<<NE / 32, 256, 0, s>>>(mem, srcv, posv, negv,
                                    lp_w1, lp_b1, lp_w2, lp_b2, d_out);
}